// Round 1
// baseline (2617.933 us; speedup 1.0000x reference)
//
#include <hip/hip_runtime.h>
#include <hip/hip_bf16.h>
#include <math.h>

#define HN 512   // hidden states
#define HM 4096  // emission symbols
#define HB 64    // batch
#define HT 512   // max seq len

__device__ __forceinline__ float wsum(float v){
  #pragma unroll
  for(int o=32;o>0;o>>=1) v += __shfl_xor(v,o,64);
  return v;
}
__device__ __forceinline__ float wmax(float v){
  #pragma unroll
  for(int o=32;o>0;o>>=1) v = fmaxf(v,__shfl_xor(v,o,64));
  return v;
}

// block of 512 threads (8 waves); returns value broadcast to all threads
__device__ __forceinline__ float blockSum512(float v, float* red, float* bc){
  v = wsum(v);
  if((threadIdx.x & 63)==0) red[threadIdx.x>>6] = v;
  __syncthreads();
  if(threadIdx.x < 64){
    float s = (threadIdx.x<8)? red[threadIdx.x] : 0.0f;
    #pragma unroll
    for(int o=4;o>0;o>>=1) s += __shfl_xor(s,o,64);
    if(threadIdx.x==0) *bc = s;
  }
  __syncthreads();
  return *bc;
}
__device__ __forceinline__ float blockMax512(float v, float* red, float* bc){
  v = wmax(v);
  if((threadIdx.x & 63)==0) red[threadIdx.x>>6] = v;
  __syncthreads();
  if(threadIdx.x < 64){
    float s = (threadIdx.x<8)? red[threadIdx.x] : -INFINITY;
    #pragma unroll
    for(int o=4;o>0;o>>=1) s = fmaxf(s, __shfl_xor(s,o,64));
    if(threadIdx.x==0) *bc = s;
  }
  __syncthreads();
  return *bc;
}

__device__ __forceinline__ unsigned short f2bf(float f){
  unsigned int u = __float_as_uint(f);
  unsigned int r = (u + 0x7fffu + ((u>>16)&1u)) >> 16;  // RNE
  return (unsigned short)r;
}
__device__ __forceinline__ float bflo(unsigned int w){ return __uint_as_float(w<<16); }
__device__ __forceinline__ float bfhi(unsigned int w){ return __uint_as_float(w & 0xffff0000u); }

// row logsumexp of emission_logits (N x M) -> em_lse[N]
__global__ __launch_bounds__(512) void k_em_lse(const float* __restrict__ em, float* __restrict__ em_lse){
  __shared__ float red[8]; __shared__ float bc;
  int r = blockIdx.x;
  const float* row = em + (size_t)r*HM;
  float mx = -INFINITY;
  for(int i=threadIdx.x;i<HM;i+=512) mx = fmaxf(mx, row[i]);
  mx = blockMax512(mx, red, &bc);
  float s = 0.f;
  for(int i=threadIdx.x;i<HM;i+=512) s += expf(row[i]-mx);
  s = blockSum512(s, red, &bc);
  if(threadIdx.x==0) em_lse[r] = mx + logf(s);
}

// prior: P[j] = exp(prior[j]-max), pric = max(log_pri) offset = -log(sum exp(prior-max))
__global__ __launch_bounds__(512) void k_pri(const float* __restrict__ pri, float* __restrict__ P, float* __restrict__ pric){
  __shared__ float red[8]; __shared__ float bc;
  int j = threadIdx.x;
  float v = pri[j];
  float mx = blockMax512(v, red, &bc);
  float w = expf(v-mx);
  float s = blockSum512(w, red, &bc);
  P[j] = w;
  if(j==0) *pric = -logf(s);
}

// per symbol m: colmax[m] = max_j log_em[j,m]; emT[m][j] = exp(log_em[j,m]-colmax[m]) in bf16
__global__ __launch_bounds__(512) void k_em_tab(const float* __restrict__ em, const float* __restrict__ em_lse,
                                                unsigned short* __restrict__ emT, float* __restrict__ colmax){
  __shared__ float red[8]; __shared__ float bc;
  int m = blockIdx.x, j = threadIdx.x;
  float v = em[(size_t)j*HM + m] - em_lse[j];
  float cm = blockMax512(v, red, &bc);
  emT[(size_t)m*HN + j] = f2bf(expf(v - cm));
  if(j==0) colmax[m] = cm;
}

// per column k: col-softmax of transition_logits; pack Tr[j][k] bf16 into
// uint4-tiles: ushort index ((k>>3)*N + j)*8 + (k&7)  => load of TrP[k8*N+j] gives
// row j, columns 8*k8..8*k8+7, coalesced across j.
__global__ __launch_bounds__(512) void k_tr(const float* __restrict__ tr, unsigned short* __restrict__ TrP){
  __shared__ float red[8]; __shared__ float bc;
  int k = blockIdx.x, j = threadIdx.x;
  float v = tr[(size_t)j*HN + k];
  float mx = blockMax512(v, red, &bc);
  float w = expf(v-mx);
  float s = blockSum512(w, red, &bc);
  TrP[((size_t)(k>>3)*HN + j)*8 + (k&7)] = f2bf(w / s);
}

// forward recurrence: one block per batch element, thread j owns state j.
__global__ __launch_bounds__(512) void k_fwd(const int* __restrict__ x, const int* __restrict__ Tl,
                                             const unsigned short* __restrict__ emT, const float* __restrict__ colmax,
                                             const float* __restrict__ P, const float* __restrict__ pric,
                                             const uint4* __restrict__ TrP, float* __restrict__ out){
  __shared__ float4 aS4[HN/4];
  __shared__ float red[8]; __shared__ float bc;
  float* aS = (float*)aS4;
  int b = blockIdx.x, j = threadIdx.x;
  const int* xb = x + b*HT;
  int Tb = Tl[b];

  // t = 0
  int m0 = xb[0];
  float e0 = bflo((unsigned)emT[(size_t)m0*HN + j]);
  float v = e0 * P[j];
  float S = blockSum512(v, red, &bc);
  float c = colmax[m0] + pric[0] + logf(S);
  aS[j] = v / S;
  __syncthreads();

  for(int t=1;t<Tb;t++){
    int m = xb[t];
    float a0=0.f,a1=0.f,a2=0.f,a3=0.f;
    const uint4* tp = TrP + j;
    #pragma unroll 4
    for(int k8=0;k8<HN/8;k8++){
      uint4 w = tp[(size_t)k8*HN];     // 8 bf16 of row j, cols 8k8..8k8+7
      float4 p0 = aS4[k8*2];
      float4 p1 = aS4[k8*2+1];
      a0 += bflo(w.x) * p0.x;
      a1 += bfhi(w.x) * p0.y;
      a2 += bflo(w.y) * p0.z;
      a3 += bfhi(w.y) * p0.w;
      a0 += bflo(w.z) * p1.x;
      a1 += bfhi(w.z) * p1.y;
      a2 += bflo(w.w) * p1.z;
      a3 += bfhi(w.w) * p1.w;
    }
    float acc = (a0+a1)+(a2+a3);
    float eo = bflo((unsigned)emT[(size_t)m*HN + j]);
    float nv = eo * acc;                     // un-normalized new alpha (linear, scaled)
    float S2 = blockSum512(nv, red, &bc);    // barrier inside => safe to overwrite aS after
    c += colmax[m] + logf(S2);
    aS[j] = nv / S2;
    __syncthreads();
  }
  if(j==0) out[b] = c;
}

extern "C" void kernel_launch(void* const* d_in, const int* in_sizes, int n_in,
                              void* d_out, int out_size, void* d_ws, size_t ws_size,
                              hipStream_t stream){
  const int*   x   = (const int*)d_in[0];
  const int*   T   = (const int*)d_in[1];
  const float* em  = (const float*)d_in[2];
  const float* tr  = (const float*)d_in[3];
  const float* pri = (const float*)d_in[4];
  float* out = (float*)d_out;

  char* ws = (char*)d_ws;
  float* em_lse = (float*)ws;                      // 512*4   = 2 KiB
  float* P      = (float*)(ws + 2048);             // 512*4   = 2 KiB
  float* pric   = (float*)(ws + 4096);             // 16 B
  float* colmax = (float*)(ws + 8192);             // 4096*4  = 16 KiB
  unsigned short* emT = (unsigned short*)(ws + 24576);                       // M*N*2 = 4 MiB
  unsigned short* TrP = (unsigned short*)(ws + 24576 + (size_t)HM*HN*2);     // N*N*2 = 512 KiB

  k_em_lse<<<HN, 512, 0, stream>>>(em, em_lse);
  k_pri  <<<1,  512, 0, stream>>>(pri, P, pric);
  k_tr   <<<HN, 512, 0, stream>>>(tr, TrP);
  k_em_tab<<<HM,512, 0, stream>>>(em, em_lse, emT, colmax);
  k_fwd  <<<HB, 512, 0, stream>>>(x, T, emT, colmax, P, pric, (const uint4*)TrP, out);
}

// Round 3
// 1352.595 us; speedup vs baseline: 1.9355x; 1.9355x over previous
//
#include <hip/hip_runtime.h>
#include <hip/hip_fp16.h>
#include <math.h>

#define HN 512   // hidden states
#define HM 4096  // emission symbols
#define HB 64    // batch
#define HT 512   // max seq len

__device__ __forceinline__ float wsum(float v){
  #pragma unroll
  for(int o=32;o>0;o>>=1) v += __shfl_xor(v,o,64);
  return v;
}
__device__ __forceinline__ float wmax(float v){
  #pragma unroll
  for(int o=32;o>0;o>>=1) v = fmaxf(v,__shfl_xor(v,o,64));
  return v;
}

__device__ __forceinline__ float blockSum512(float v, float* red, float* bc){
  v = wsum(v);
  if((threadIdx.x & 63)==0) red[threadIdx.x>>6] = v;
  __syncthreads();
  if(threadIdx.x < 64){
    float s = (threadIdx.x<8)? red[threadIdx.x] : 0.0f;
    #pragma unroll
    for(int o=4;o>0;o>>=1) s += __shfl_xor(s,o,64);
    if(threadIdx.x==0) *bc = s;
  }
  __syncthreads();
  return *bc;
}
__device__ __forceinline__ float blockMax512(float v, float* red, float* bc){
  v = wmax(v);
  if((threadIdx.x & 63)==0) red[threadIdx.x>>6] = v;
  __syncthreads();
  if(threadIdx.x < 64){
    float s = (threadIdx.x<8)? red[threadIdx.x] : -INFINITY;
    #pragma unroll
    for(int o=4;o>0;o>>=1) s = fmaxf(s, __shfl_xor(s,o,64));
    if(threadIdx.x==0) *bc = s;
  }
  __syncthreads();
  return *bc;
}

__device__ __forceinline__ unsigned short f2bf(float f){
  unsigned int u = __float_as_uint(f);
  unsigned int r = (u + 0x7fffu + ((u>>16)&1u)) >> 16;  // RNE
  return (unsigned short)r;
}
__device__ __forceinline__ float bf2f(unsigned int w){ return __uint_as_float(w<<16); }

__device__ __forceinline__ __half2 u2h2(unsigned int u){ union{unsigned int u; __half2 h;} c; c.u=u; return c.h; }

__device__ __forceinline__ __half2 pkh2(float a, float b){
#if __has_builtin(__builtin_amdgcn_cvt_pkrtz)
  auto r = __builtin_amdgcn_cvt_pkrtz(a, b);
  union{ decltype(r) v; __half2 h; } c; c.v = r; return c.h;
#else
  return __floats2half2_rn(a, b);
#endif
}

__device__ __forceinline__ float f8dec(unsigned int b){
  unsigned e = (b>>3)&15u, m = b&7u;
  float v = e ? ldexpf(8.0f + (float)m, (int)e - 10) : ldexpf((float)m, -9);
  return (b & 0x80u) ? -v : v;
}
template<bool HI>
__device__ __forceinline__ void f8pair(unsigned int dw, float& a, float& b){
#if __has_builtin(__builtin_amdgcn_cvt_pk_f32_fp8)
  auto r = __builtin_amdgcn_cvt_pk_f32_fp8((int)dw, HI);
  a = r[0]; b = r[1];
#else
  unsigned int s = HI ? (dw>>16) : dw;
  a = f8dec(s & 0xffu); b = f8dec((s>>8)&0xffu);
#endif
}
__device__ __forceinline__ unsigned char f8enc(float v){
#if __has_builtin(__builtin_amdgcn_cvt_pk_fp8_f32)
  int p = __builtin_amdgcn_cvt_pk_fp8_f32(v, v, 0, false);
  return (unsigned char)(p & 0xff);
#else
  if(!(v > 0.0f)) return 0;
  if(v >= 448.0f) return 0x7e;
  int e; frexpf(v, &e);          // 2^(e-1) <= v < 2^e
  int E = e + 6;                 // biased exponent
  if(E <= 0){
    float q = rintf(ldexpf(v, 9));
    return (unsigned char)q;     // q==8 rolls into E=1,m=0 correctly
  }
  float q = rintf(ldexpf(v, 4 - e));  // mant in [8,16)
  if(q >= 16.0f){ E++; q = 8.0f; }
  if(E > 15) return 0x7e;
  return (unsigned char)((E<<3) | ((int)q - 8));
#endif
}

// ---------------- prep kernels ----------------

__global__ __launch_bounds__(512) void k_em_lse(const float* __restrict__ em, float* __restrict__ em_lse){
  __shared__ float red[8]; __shared__ float bc;
  int r = blockIdx.x;
  const float* row = em + (size_t)r*HM;
  float mx = -INFINITY;
  for(int i=threadIdx.x;i<HM;i+=512) mx = fmaxf(mx, row[i]);
  mx = blockMax512(mx, red, &bc);
  float s = 0.f;
  for(int i=threadIdx.x;i<HM;i+=512) s += expf(row[i]-mx);
  s = blockSum512(s, red, &bc);
  if(threadIdx.x==0) em_lse[r] = mx + logf(s);
}

__global__ __launch_bounds__(512) void k_pri(const float* __restrict__ pri, float* __restrict__ P, float* __restrict__ pric){
  __shared__ float red[8]; __shared__ float bc;
  int j = threadIdx.x;
  float v = pri[j];
  float mx = blockMax512(v, red, &bc);
  float w = expf(v-mx);
  float s = blockSum512(w, red, &bc);
  P[j] = w;
  if(j==0) *pric = -logf(s);
}

__global__ __launch_bounds__(512) void k_em_tab(const float* __restrict__ em, const float* __restrict__ em_lse,
                                                unsigned short* __restrict__ emT, float* __restrict__ colmax){
  __shared__ float red[8]; __shared__ float bc;
  int m = blockIdx.x, j = threadIdx.x;
  float v = em[(size_t)j*HM + m] - em_lse[j];
  float cm = blockMax512(v, red, &bc);
  emT[(size_t)m*HN + j] = f2bf(expf(v - cm));
  if(j==0) colmax[m] = cm;
}

// col-softmax of transition; emit scaled (x256) f16-pair table (reg part, j%8<5)
// and scaled fp8 table (LDS part, j%8>=5).
__global__ __launch_bounds__(512) void k_tr(const float* __restrict__ tr,
                                            unsigned short* __restrict__ G1,
                                            unsigned char* __restrict__ L8){
  __shared__ float red[8]; __shared__ float bc;
  int k = blockIdx.x, j = threadIdx.x;
  float v = tr[(size_t)j*HN + k];
  float mx = blockMax512(v, red, &bc);
  float wv = expf(v-mx);
  float s = blockSum512(wv, red, &bc);
  float p = 256.0f * (wv / s);          // scaled prob
  int w = k>>6, kl = k&63, k2 = kl>>1, l = j>>3, i = j&7;
  if(i < 5){
    unsigned short h = __half_as_ushort(__float2half(p));
    G1[((size_t)((w*5+i)*32 + k2)*64 + l)*2 + (kl&1)] = h;
  } else {
    L8[((size_t)(((w*3)+(i-5))*4 + (kl>>4))*64 + l)*16 + (kl&15)] = f8enc(p);
  }
}

// ---------------- forward recurrence ----------------
__global__ __launch_bounds__(512) void k_fwd(const int* __restrict__ x, const int* __restrict__ Tl,
                                             const unsigned short* __restrict__ emTu,
                                             const float* __restrict__ colmax,
                                             const float* __restrict__ P, const float* __restrict__ pric,
                                             const unsigned int* __restrict__ G1u,
                                             const uint4* __restrict__ Lfp8,
                                             float* __restrict__ out){
  extern __shared__ char smem[];
  uint4*  ah4  = (uint4*)smem;
  unsigned short* ah16 = (unsigned short*)smem;
  float*  red2 = (float*)(smem + 1024);
  int*    xls  = (int*)(smem + 1088);
  float*  red  = (float*)(smem + 3136);
  uint4*  trl  = (uint4*)(smem + 19520);

  const int t = threadIdx.x, w = t>>6, l = t&63, b = blockIdx.x;

  xls[t] = x[b*HT + t];
  for(int i=t;i<6144;i+=512) trl[i] = Lfp8[i];

  unsigned int trr[160];
  #pragma unroll
  for(int r=0;r<160;r++) trr[r] = G1u[(w*160 + r)*64 + l];

  int Tb = Tl[b];
  __syncthreads();

  int   m   = xls[0];
  float e   = bf2f((unsigned)emTu[(size_t)m*HN + t]);
  float cmx = colmax[m];
  float nu  = e * P[t];
  {
    float vs = wsum(nu);
    if(l==0) red2[w] = vs;
  }
  __syncthreads();
  float4 r0 = ((float4*)red2)[0], r1 = ((float4*)red2)[1];
  float S = ((r0.x+r0.y)+(r0.z+r0.w))+((r1.x+r1.y)+(r1.z+r1.w));
  float c = cmx + pric[0] + __logf(S);
  float sc = 256.0f / S;
  ah16[t] = __half_as_ushort(__float2half(nu * sc));
  int   mn  = xls[(Tb>1)?1:0];
  float en  = bf2f((unsigned)emTu[(size_t)mn*HN + t]);
  float cmn = colmax[mn];
  __syncthreads();

  for(int tt=1; tt<Tb; tt++){
    m = mn; e = en; cmx = cmn;
    int tnx = (tt+1 < HT)? tt+1 : HT-1;
    mn  = xls[tnx];
    en  = bf2f((unsigned)emTu[(size_t)mn*HN + t]);
    cmn = colmax[mn];

    unsigned int apk[32];
    {
      uint4* ap4 = (uint4*)apk;
      #pragma unroll
      for(int q=0;q<8;q++) ap4[q] = ah4[8*w + q];
    }
    __half2 acc[8];
    #pragma unroll
    for(int i=0;i<8;i++) acc[i] = u2h2(0u);

    #pragma unroll
    for(int i=0;i<5;i++){
      #pragma unroll
      for(int k2=0;k2<32;k2++){
        acc[i] = __hfma2(u2h2(trr[i*32+k2]), u2h2(apk[k2]), acc[i]);
      }
    }
    #pragma unroll
    for(int i5=0;i5<3;i5++){
      #pragma unroll
      for(int q=0;q<4;q++){
        uint4 F = trl[(w*12 + i5*4 + q)*64 + l];
        unsigned int dws[4] = {F.x, F.y, F.z, F.w};
        #pragma unroll
        for(int d=0; d<4; d++){
          int k2b = 8*q + 2*d;
          float fa, fb;
          f8pair<false>(dws[d], fa, fb);
          acc[5+i5] = __hfma2(pkh2(fa,fb), u2h2(apk[k2b]), acc[5+i5]);
          f8pair<true>(dws[d], fa, fb);
          acc[5+i5] = __hfma2(pkh2(fa,fb), u2h2(apk[k2b+1]), acc[5+i5]);
        }
      }
    }
    float s0 = __low2float(acc[0]) + __high2float(acc[0]);
    float s1 = __low2float(acc[1]) + __high2float(acc[1]);
    float s2 = __low2float(acc[2]) + __high2float(acc[2]);
    float s3 = __low2float(acc[3]) + __high2float(acc[3]);
    float s4 = __low2float(acc[4]) + __high2float(acc[4]);
    float s5 = __low2float(acc[5]) + __high2float(acc[5]);
    float s6 = __low2float(acc[6]) + __high2float(acc[6]);
    float s7 = __low2float(acc[7]) + __high2float(acc[7]);
    float4* rp = (float4*)&red[w*512 + 8*l];
    rp[0] = make_float4(s0,s1,s2,s3);
    rp[1] = make_float4(s4,s5,s6,s7);
    __syncthreads();                       // B1

    float v = 0.f;
    #pragma unroll
    for(int ww=0;ww<8;ww++) v += red[ww*512 + t];
    v *= (1.0f/65536.0f);
    nu = v * e;
    {
      float vs = wsum(nu);
      if(l==0) red2[w] = vs;
    }
    __syncthreads();                       // B2
    float4 q0 = ((float4*)red2)[0], q1 = ((float4*)red2)[1];
    S = ((q0.x+q0.y)+(q0.z+q0.w))+((q1.x+q1.y)+(q1.z+q1.w));
    c += cmx + __logf(S);
    sc = 256.0f / S;
    ah16[t] = __half_as_ushort(__float2half(nu * sc));
    __syncthreads();                       // B3
  }
  if(t==0) out[b] = c;
}

extern "C" void kernel_launch(void* const* d_in, const int* in_sizes, int n_in,
                              void* d_out, int out_size, void* d_ws, size_t ws_size,
                              hipStream_t stream){
  const int*   x   = (const int*)d_in[0];
  const int*   T   = (const int*)d_in[1];
  const float* em  = (const float*)d_in[2];
  const float* tr  = (const float*)d_in[3];
  const float* pri = (const float*)d_in[4];
  float* out = (float*)d_out;

  char* ws = (char*)d_ws;
  float* em_lse = (float*)ws;
  float* P      = (float*)(ws + 2048);
  float* pric   = (float*)(ws + 4096);
  float* colmax = (float*)(ws + 8192);
  unsigned short* emT = (unsigned short*)(ws + 24576);
  unsigned short* G1  = (unsigned short*)(ws + 24576 + (size_t)HM*HN*2);
  unsigned char*  L8  = (unsigned char*)(ws + 24576 + (size_t)HM*HN*2 + 327680);

  k_em_lse<<<HN, 512, 0, stream>>>(em, em_lse);
  k_pri  <<<1,  512, 0, stream>>>(pri, P, pric);
  k_tr   <<<HN, 512, 0, stream>>>(tr, G1, L8);
  k_em_tab<<<HM,512, 0, stream>>>(em, em_lse, emT, colmax);

  const int lds_bytes = 19520 + 98304;
  (void)hipFuncSetAttribute((const void*)k_fwd, hipFuncAttributeMaxDynamicSharedMemorySize, lds_bytes);
  k_fwd  <<<HB, 512, lds_bytes, stream>>>(x, T, emT, colmax, P, pric,
                                          (const unsigned int*)G1, (const uint4*)L8, out);
}